// Round 2
// baseline (1139.093 us; speedup 1.0000x reference)
//
#include <hip/hip_runtime.h>

#define GH 13
#define GW 3
#define GCELLS 39
#define ENC 128
#define TST 16
#define KNB 32
#define C31 16
#define C11 32
#define POOLH 5
#define FCD 160   // C11 * POOLH * 1
#define OUTD 64
#define BLK 256

__device__ __forceinline__ float lrelu(float x) { return x > 0.f ? x : 0.1f * x; }

__global__ __launch_bounds__(BLK) void csp_fused_kernel(
    const float* __restrict__ enc,   // (NV, 128, 16)
    const int*   __restrict__ nb,    // (B, 32)
    const int*   __restrict__ gp,    // (NV, 2)
    const float* __restrict__ w31,   // (16, 128, 3, 1)
    const float* __restrict__ b31,   // (16)
    const float* __restrict__ w11,   // (32, 16, 1, 1)
    const float* __restrict__ b11,   // (32)
    const float* __restrict__ fc_w,  // (64, 160)
    const float* __restrict__ fc_b,  // (64)
    float* __restrict__ out)         // (B, 64)
{
    __shared__ int   winner_s[GCELLS];
    __shared__ __align__(16) float soc_s[GCELLS][132];     // [cell][c], pad 132
    __shared__ __align__(16) float w31_s[C31][3][132];     // [oc][dh][c], pad 132
    __shared__ __align__(16) float out16_s[GCELLS][C31];   // [pos][oc]
    __shared__ __align__(16) float pooled_s[FCD];          // [c2*5 + ph]
    __shared__ __align__(16) float red_s[BLK];

    const int b = blockIdx.x;
    const int t = threadIdx.x;

    // ---- phase 1: init winners ----
    if (t < GCELLS) winner_s[t] = -1;
    __syncthreads();

    // ---- phase 2: scatter-max winners (k index, max wins) ----
    if (t < KNB) {
        int veh = nb[b * KNB + t];
        int x = gp[veh * 2 + 0];
        int y = gp[veh * 2 + 1];
        if (x >= 0 && x < GH && y >= 0 && y < GW)
            atomicMax(&winner_s[x * GW + y], t);
    }
    // stage reorganized conv31 weights concurrently (no dep on winners)
    for (int idx = t; idx < C31 * ENC * 3; idx += BLK) {
        int oc  = idx / (ENC * 3);
        int rem = idx - oc * (ENC * 3);
        int c   = rem / 3;
        int dh  = rem - c * 3;
        w31_s[oc][dh][c] = w31[idx];   // src layout [oc][c][dh] flat == idx
    }
    __syncthreads();

    // ---- phase 3: gather features into soc grid (zeros for empty cells) ----
    for (int idx = t; idx < GCELLS * ENC; idx += BLK) {
        int g = idx >> 7;       // cell
        int c = idx & 127;      // channel
        int w = winner_s[g];
        float v = 0.f;
        if (w >= 0) {
            int veh = nb[b * KNB + w];
            v = enc[(veh * ENC + c) * TST + (TST - 1)];
        }
        soc_s[g][c] = v;
    }
    __syncthreads();

    // ---- phase 4: conv 3x1 (pad H by 1) + bias + lrelu ----
    {
        const int i = t & 15;        // output channel
        const int j = t >> 4;        // position group: p = j, j+16, j+32
        const int p0 = j, p1 = j + 16, p2 = j + 32;
        const int h0 = p0 / 3, w0 = p0 - h0 * 3;
        const int h1 = p1 / 3, w1 = p1 - h1 * 3;
        const int h2 = p2 / 3, w2 = p2 - h2 * 3;
        const bool has2 = (p2 < GCELLS);

        const float bias = b31[i];
        float a0 = bias, a1 = bias, a2 = bias;

        for (int dh = 0; dh < 3; ++dh) {
            const int q0 = h0 + dh - 1, q1 = h1 + dh - 1, q2 = h2 + dh - 1;
            const bool v0 = (q0 >= 0) & (q0 < GH);
            const bool v1 = (q1 >= 0) & (q1 < GH);
            const bool v2 = has2 & (q2 >= 0) & (q2 < GH);
            const float4* wp = (const float4*)&w31_s[i][dh][0];
            const float4* s0 = (const float4*)&soc_s[(q0 * GW + w0) & 63][0];
            const float4* s1 = (const float4*)&soc_s[(q1 * GW + w1) & 63][0];
            const float4* s2 = (const float4*)&soc_s[(q2 * GW + w2) & 63][0];
            #pragma unroll 8
            for (int c4 = 0; c4 < ENC / 4; ++c4) {
                float4 wv = wp[c4];
                if (v0) { float4 s = s0[c4]; a0 += wv.x*s.x + wv.y*s.y + wv.z*s.z + wv.w*s.w; }
                if (v1) { float4 s = s1[c4]; a1 += wv.x*s.x + wv.y*s.y + wv.z*s.z + wv.w*s.w; }
                if (v2) { float4 s = s2[c4]; a2 += wv.x*s.x + wv.y*s.y + wv.z*s.z + wv.w*s.w; }
            }
        }
        out16_s[p0][i] = lrelu(a0);
        out16_s[p1][i] = lrelu(a1);
        if (has2) out16_s[p2][i] = lrelu(a2);
    }
    __syncthreads();

    // ---- phase 5: conv 1x1 + bias + lrelu + 3x3/3 maxpool (H pad (0,2)) ----
    {
        const int c2 = t & 31;
        const int ph = t >> 5;
        if (ph < POOLH) {
            float wreg[C31];
            #pragma unroll
            for (int c = 0; c < C31; ++c) wreg[c] = w11[c2 * C31 + c];
            const float bias2 = b11[c2];
            float mx = -1e30f;
            const int hend = (3 * ph + 3 < GH) ? 3 * ph + 3 : GH;
            for (int h = 3 * ph; h < hend; ++h) {
                for (int w = 0; w < GW; ++w) {
                    const float* o16 = &out16_s[h * GW + w][0];
                    float s = bias2;
                    #pragma unroll
                    for (int c = 0; c < C31; ++c) s += o16[c] * wreg[c];
                    s = lrelu(s);
                    mx = fmaxf(mx, s);
                }
            }
            pooled_s[c2 * POOLH + ph] = mx;
        }
    }
    __syncthreads();

    // ---- phase 6: FC 160 -> 64 + bias + lrelu ----
    {
        const int o = t & 63;
        const int q = t >> 6;       // quarter of the 160-dim
        const float4* fw = (const float4*)&fc_w[o * FCD + q * 40];
        const float4* ps = (const float4*)&pooled_s[q * 40];
        float s = 0.f;
        #pragma unroll
        for (int r = 0; r < 10; ++r) {
            float4 w = fw[r];
            float4 p = ps[r];
            s += w.x*p.x + w.y*p.y + w.z*p.z + w.w*p.w;
        }
        red_s[t] = s;
    }
    __syncthreads();
    if (t < OUTD) {
        float s = red_s[t] + red_s[t + 64] + red_s[t + 128] + red_s[t + 192] + fc_b[t];
        out[b * OUTD + t] = lrelu(s);
    }
}

extern "C" void kernel_launch(void* const* d_in, const int* in_sizes, int n_in,
                              void* d_out, int out_size, void* d_ws, size_t ws_size,
                              hipStream_t stream) {
    const float* enc  = (const float*)d_in[0];
    const int*   nb   = (const int*)d_in[1];
    const int*   gp   = (const int*)d_in[2];
    const float* w31  = (const float*)d_in[3];
    const float* b31  = (const float*)d_in[4];
    const float* w11  = (const float*)d_in[5];
    const float* b11  = (const float*)d_in[6];
    const float* fc_w = (const float*)d_in[7];
    const float* fc_b = (const float*)d_in[8];
    float* out = (float*)d_out;

    const int B = in_sizes[1] / KNB;   // 8192
    csp_fused_kernel<<<B, BLK, 0, stream>>>(enc, nb, gp, w31, b31, w11, b11,
                                            fc_w, fc_b, out);
}